// Round 5
// baseline (676.875 us; speedup 1.0000x reference)
//
#include <hip/hip_runtime.h>

#define Hm 2048
#define Em 64
#define Tm 32768
#define KSEL 640        // int(1.25 * 32768 / 64)
#define CHK 16          // k per staged chunk

typedef unsigned int u32;

__device__ __forceinline__ float4 ld4(const float* p) {
    return *reinterpret_cast<const float4*>(p);
}

// ---------------------------------------------------------------------------
// K0: W [64][2048] -> Wt [2048][64] (k-major, one-time)
// ---------------------------------------------------------------------------
__global__ __launch_bounds__(256) void k_wt(
    const float* __restrict__ W, float* __restrict__ Wt)
{
    __shared__ float T[64][65];
    const int tid = threadIdx.x;
    const int kb = blockIdx.x * 64;
    const int lc = tid & 63;
    const int lr = tid >> 6;
#pragma unroll
    for (int r = 0; r < 16; ++r) {
        const int e = r * 4 + lr;
        T[e][lc] = W[(size_t)e * Hm + kb + lc];
    }
    __syncthreads();
#pragma unroll
    for (int r = 0; r < 16; ++r) {
        const int kk = r * 4 + lr;
        Wt[(size_t)(kb + kk) * Em + lc] = T[lc][kk];
    }
}

// ---------------------------------------------------------------------------
// K1: split-K partial GEMM. grid = 256*nkq blocks x 128 threads (2 waves).
// Wave = 64 tok x 64 exp; thread tile = 8 tok x 8 exp (lane grid 8x8) ->
// every LDS fragment read is 8-way broadcast, 2-way bank alias (free).
// A staged k-major As[k][tok] via stride-1 scalar writes; B linear copy.
// Partials pl[kq][T][E] (fp32) reduced by k_reduce.
// ---------------------------------------------------------------------------
__global__ __launch_bounds__(128, 4) void k_router_partial(
    const float* __restrict__ hid, const float* __restrict__ Wt,
    float* __restrict__ pl, int nkq)
{
    __shared__ __align__(16) float As[CHK][132];   // 8.4 KB (k-major, pad 4)
    __shared__ __align__(16) float Bs[CHK][68];    // 4.3 KB

    const int t = threadIdx.x;
    const int tb = blockIdx.x & 255;
    const int kq = blockIdx.x >> 8;
    const int t0 = tb * 128;
    const int k0 = kq * (Hm / nkq);
    const int nchunks = (Hm / nkq) / CHK;

    const float* ap = hid + (size_t)(t0 + t) * Hm + k0;
    const float* bp = Wt + (size_t)k0 * Em + t * 8;

    float acc[8][8];
#pragma unroll
    for (int i = 0; i < 8; ++i)
#pragma unroll
        for (int j = 0; j < 8; ++j) acc[i][j] = 0.f;

    float ar[16];
    float4 br0, br1;

    auto loadA = [&](int c) {
#pragma unroll
        for (int u = 0; u < 4; ++u) {
            const float4 v = ld4(ap + c * CHK + 4 * u);
            ar[4 * u + 0] = v.x; ar[4 * u + 1] = v.y;
            ar[4 * u + 2] = v.z; ar[4 * u + 3] = v.w;
        }
    };
    auto loadB = [&](int c) {
        const float* b = bp + (size_t)c * (CHK * Em);
        br0 = ld4(b);
        br1 = ld4(b + 4);
    };
    auto writeAB = [&]() {
#pragma unroll
        for (int kk = 0; kk < CHK; ++kk) As[kk][t] = ar[kk];
        *reinterpret_cast<float4*>(&Bs[t >> 3][(t & 7) * 8])     = br0;
        *reinterpret_cast<float4*>(&Bs[t >> 3][(t & 7) * 8 + 4]) = br1;
    };

    const int l  = t & 63;
    const int w  = t >> 6;
    const int lr = l >> 3;
    const int lc = l & 7;
    const int ta = w * 64 + lr * 8;   // token base within block tile

    loadA(0); loadB(0);

    for (int c = 0; c < nchunks; ++c) {
        writeAB();
        __syncthreads();
        if (c + 1 < nchunks) { loadA(c + 1); loadB(c + 1); }

#pragma unroll
        for (int kk = 0; kk < CHK; ++kk) {
            const float4 a0 = ld4(&As[kk][ta]);
            const float4 a1 = ld4(&As[kk][ta + 4]);
            const float4 b0 = ld4(&Bs[kk][lc * 8]);
            const float4 b1 = ld4(&Bs[kk][lc * 8 + 4]);
            const float av[8] = { a0.x, a0.y, a0.z, a0.w,
                                  a1.x, a1.y, a1.z, a1.w };
            const float bv[8] = { b0.x, b0.y, b0.z, b0.w,
                                  b1.x, b1.y, b1.z, b1.w };
#pragma unroll
            for (int i = 0; i < 8; ++i)
#pragma unroll
                for (int j = 0; j < 8; ++j)
                    acc[i][j] = fmaf(av[i], bv[j], acc[i][j]);
        }
        __syncthreads();
    }

    // epilogue: write partials
#pragma unroll
    for (int i = 0; i < 8; ++i) {
        float* dst = pl + ((size_t)kq * Tm + t0 + ta + i) * Em + lc * 8;
        *reinterpret_cast<float4*>(dst) =
            make_float4(acc[i][0], acc[i][1], acc[i][2], acc[i][3]);
        *reinterpret_cast<float4*>(dst + 4) =
            make_float4(acc[i][4], acc[i][5], acc[i][6], acc[i][7]);
    }
}

// ---------------------------------------------------------------------------
// K1b: reduce split-K partials + softmax. One thread per token.
// grid = 128 x 256. Writes probs [T][E] and probsT [E][T] (coalesced).
// ---------------------------------------------------------------------------
__global__ __launch_bounds__(256) void k_reduce(
    const float* __restrict__ pl, int nkq,
    float* __restrict__ probs, float* __restrict__ probsT)
{
    const int t = blockIdx.x * 256 + threadIdx.x;
    float lg[64];
    {
        const float* src = pl + (size_t)t * Em;
#pragma unroll
        for (int j = 0; j < 16; ++j) {
            const float4 x = ld4(src + 4 * j);
            lg[4 * j + 0] = x.x; lg[4 * j + 1] = x.y;
            lg[4 * j + 2] = x.z; lg[4 * j + 3] = x.w;
        }
    }
    for (int q = 1; q < nkq; ++q) {
        const float* src = pl + ((size_t)q * Tm + t) * Em;
#pragma unroll
        for (int j = 0; j < 16; ++j) {
            const float4 x = ld4(src + 4 * j);
            lg[4 * j + 0] += x.x; lg[4 * j + 1] += x.y;
            lg[4 * j + 2] += x.z; lg[4 * j + 3] += x.w;
        }
    }
    float mx = lg[0];
#pragma unroll
    for (int e = 1; e < 64; ++e) mx = fmaxf(mx, lg[e]);
    float s = 0.f;
#pragma unroll
    for (int e = 0; e < 64; ++e) { lg[e] = __expf(lg[e] - mx); s += lg[e]; }
    const float inv = 1.0f / s;
#pragma unroll
    for (int e = 0; e < 64; ++e) lg[e] *= inv;

    float* po = probs + (size_t)t * Em;
#pragma unroll
    for (int j = 0; j < 16; ++j)
        *reinterpret_cast<float4*>(po + 4 * j) =
            make_float4(lg[4 * j], lg[4 * j + 1], lg[4 * j + 2], lg[4 * j + 3]);
    if (probsT) {
#pragma unroll
        for (int e = 0; e < 64; ++e)
            probsT[(size_t)e * Tm + t] = lg[e];
    }
}

// ---------------------------------------------------------------------------
// K2: per-expert top-640 radix select (10/11/11 bits).
// dT path: write full coalesced rows dT[e][t] (no pre-zero needed).
// ---------------------------------------------------------------------------
__device__ __forceinline__ void suffix_scan(u32* h, int nbins) {
    const int tid = threadIdx.x;
    for (int off = 1; off < nbins; off <<= 1) {
        u32 v0 = 0, v1 = 0;
        const int b0 = tid, b1 = tid + 1024;
        if (b0 < nbins) v0 = h[b0] + ((b0 + off) < nbins ? h[b0 + off] : 0u);
        if (b1 < nbins) v1 = h[b1] + ((b1 + off) < nbins ? h[b1 + off] : 0u);
        __syncthreads();
        if (b0 < nbins) h[b0] = v0;
        if (b1 < nbins) h[b1] = v1;
        __syncthreads();
    }
}

__global__ __launch_bounds__(1024) void k_select(
    const float* __restrict__ probsT, const float* __restrict__ probsRM,
    float* __restrict__ dispatch, float* __restrict__ dT)
{
    __shared__ u32 keys[Tm];        // 128 KB
    __shared__ u32 hist[2048];      // 8 KB (reused as tie list)
    __shared__ u32 sh_need[4];
    __shared__ u32 sh_bins[3];
    __shared__ u32 sh_ntie, sh_take, sh_nlist;

    const int tid = threadIdx.x;
    const int e = blockIdx.x;

    if (probsT) {
        const float4* src = reinterpret_cast<const float4*>(probsT + (size_t)e * Tm);
        for (int i = tid; i < Tm / 4; i += 1024) {
            float4 x = src[i];
            uint4 kk = make_uint4(__float_as_uint(x.x), __float_as_uint(x.y),
                                  __float_as_uint(x.z), __float_as_uint(x.w));
            *reinterpret_cast<uint4*>(&keys[4 * i]) = kk;
        }
    } else {
        for (int t = tid; t < Tm; t += 1024)
            keys[t] = __float_as_uint(probsRM[(size_t)t * Em + e]);
    }

    // pass 1: bits [31:22]
    hist[tid] = 0;
    if (tid == 0) sh_need[0] = KSEL;
    __syncthreads();
    for (int t = tid; t < Tm; t += 1024)
        atomicAdd(&hist[keys[t] >> 22], 1u);
    __syncthreads();
    suffix_scan(hist, 1024);
    {
        const u32 need = sh_need[0];
        if (tid < 1024) {
            const u32 sb = hist[tid];
            const u32 sa = (tid + 1 < 1024) ? hist[tid + 1] : 0u;
            if (sb >= need && sa < need) { sh_bins[0] = (u32)tid; sh_need[1] = need - sa; }
        }
    }
    __syncthreads();
    const u32 b1 = sh_bins[0];

    // pass 2: bits [21:11]
    hist[tid] = 0; hist[tid + 1024] = 0;
    __syncthreads();
    for (int t = tid; t < Tm; t += 1024) {
        const u32 k = keys[t];
        if ((k >> 22) == b1) atomicAdd(&hist[(k >> 11) & 0x7FFu], 1u);
    }
    __syncthreads();
    suffix_scan(hist, 2048);
    {
        const u32 need = sh_need[1];
#pragma unroll
        for (int r = 0; r < 2; ++r) {
            const int b = tid + r * 1024;
            const u32 sb = hist[b];
            const u32 sa = (b + 1 < 2048) ? hist[b + 1] : 0u;
            if (sb >= need && sa < need) { sh_bins[1] = (u32)b; sh_need[2] = need - sa; }
        }
    }
    __syncthreads();
    const u32 p2 = (b1 << 11) | sh_bins[1];

    // pass 3: bits [10:0]
    hist[tid] = 0; hist[tid + 1024] = 0;
    __syncthreads();
    for (int t = tid; t < Tm; t += 1024) {
        const u32 k = keys[t];
        if ((k >> 11) == p2) atomicAdd(&hist[k & 0x7FFu], 1u);
    }
    __syncthreads();
    suffix_scan(hist, 2048);
    {
        const u32 need = sh_need[2];
#pragma unroll
        for (int r = 0; r < 2; ++r) {
            const int b = tid + r * 1024;
            const u32 sb = hist[b];
            const u32 sa = (b + 1 < 2048) ? hist[b + 1] : 0u;
            if (sb >= need && sa < need) {
                sh_bins[2] = (u32)b;
                sh_take = need - sa;
                sh_ntie = sb - sa;
            }
        }
    }
    __syncthreads();
    const u32 Kstar = (p2 << 11) | sh_bins[2];
    const u32 take = sh_take, ntie = sh_ntie;

    if (dT) {
        float* drow = dT + (size_t)e * Tm;
        if (ntie == take) {
            for (int t = tid; t < Tm; t += 1024) {
                const u32 k = keys[t];
                drow[t] = (k >= Kstar) ? __uint_as_float(k) : 0.f;
            }
        } else {
            if (tid == 0) sh_nlist = 0;
            __syncthreads();
            for (int t = tid; t < Tm; t += 1024) {
                const u32 k = keys[t];
                drow[t] = (k > Kstar) ? __uint_as_float(k) : 0.f;
                if (k == Kstar) {
                    const u32 idx = atomicAdd(&sh_nlist, 1u);
                    if (idx < 2048u) hist[idx] = (u32)t;
                }
            }
            __syncthreads();
            const int n = (int)(sh_nlist < 2048u ? sh_nlist : 2048u);
            for (int i = tid; i < n; i += 1024) {
                const u32 t = hist[i];
                int r = 0;
                for (int j = 0; j < n; ++j) r += (hist[j] < t);
                if (r < (int)take) drow[t] = __uint_as_float(Kstar);
            }
        }
    } else {
        if (ntie == take) {
            for (int t = tid; t < Tm; t += 1024) {
                const u32 k = keys[t];
                if (k >= Kstar) dispatch[(size_t)t * Em + e] = __uint_as_float(k);
            }
        } else {
            if (tid == 0) sh_nlist = 0;
            __syncthreads();
            for (int t = tid; t < Tm; t += 1024) {
                const u32 k = keys[t];
                if (k > Kstar) {
                    dispatch[(size_t)t * Em + e] = __uint_as_float(k);
                } else if (k == Kstar) {
                    const u32 idx = atomicAdd(&sh_nlist, 1u);
                    if (idx < 2048u) hist[idx] = (u32)t;
                }
            }
            __syncthreads();
            const int n = (int)(sh_nlist < 2048u ? sh_nlist : 2048u);
            for (int i = tid; i < n; i += 1024) {
                const u32 t = hist[i];
                int r = 0;
                for (int j = 0; j < n; ++j) r += (hist[j] < t);
                if (r < (int)take)
                    dispatch[(size_t)t * Em + e] = __uint_as_float(Kstar);
            }
        }
    }
}

// ---------------------------------------------------------------------------
// K3a (dT path): transpose dT [E][T] -> dispatch [T][E] + combine, fused.
// ---------------------------------------------------------------------------
__global__ __launch_bounds__(256) void k_finish(
    const float* __restrict__ dT, float* __restrict__ dispatch,
    float* __restrict__ combine)
{
    __shared__ float Ls[64][65];
    const int tid = threadIdx.x;
    const int t0 = blockIdx.x * 64;
    {
        const int e = tid >> 2, tq = tid & 3;
        const float* src = dT + (size_t)e * Tm + t0 + tq * 16;
#pragma unroll
        for (int u = 0; u < 4; ++u) {
            const float4 x = ld4(src + 4 * u);
            Ls[tq * 16 + 4 * u + 0][e] = x.x;
            Ls[tq * 16 + 4 * u + 1][e] = x.y;
            Ls[tq * 16 + 4 * u + 2][e] = x.z;
            Ls[tq * 16 + 4 * u + 3][e] = x.w;
        }
    }
    __syncthreads();
    const int t = tid >> 2, q = tid & 3;
    float v[16];
    float s = 0.f;
#pragma unroll
    for (int u = 0; u < 16; ++u) { v[u] = Ls[t][q * 16 + u]; s += v[u]; }
    s += __shfl_xor(s, 1, 4);
    s += __shfl_xor(s, 2, 4);
    const float inv = (s > 0.f) ? 1.0f / s : 0.f;
    float* dp = dispatch + (size_t)(t0 + t) * Em + q * 16;
    float* cb = combine  + (size_t)(t0 + t) * Em + q * 16;
#pragma unroll
    for (int u = 0; u < 4; ++u) {
        *reinterpret_cast<float4*>(dp + 4 * u) =
            make_float4(v[4 * u], v[4 * u + 1], v[4 * u + 2], v[4 * u + 3]);
        *reinterpret_cast<float4*>(cb + 4 * u) =
            make_float4(v[4 * u] * inv, v[4 * u + 1] * inv,
                        v[4 * u + 2] * inv, v[4 * u + 3] * inv);
    }
}

// ---------------------------------------------------------------------------
// K3b (fallback): combine from dispatch rows.
// ---------------------------------------------------------------------------
__global__ __launch_bounds__(256) void k_combine(
    const float* __restrict__ dispatch, float* __restrict__ combine)
{
    const int wid = threadIdx.x >> 6;
    const int lane = threadIdx.x & 63;
    const int t = blockIdx.x * 4 + wid;
    const float d = dispatch[(size_t)t * Em + lane];
    float s = d;
#pragma unroll
    for (int off = 32; off > 0; off >>= 1) s += __shfl_xor(s, off, 64);
    combine[(size_t)t * Em + lane] = (s > 0.f) ? d / s : 0.f;
}

// ---------------------------------------------------------------------------
extern "C" void kernel_launch(void* const* d_in, const int* in_sizes, int n_in,
                              void* d_out, int out_size, void* d_ws, size_t ws_size,
                              hipStream_t stream) {
    const float* hid = (const float*)d_in[0];
    const float* W   = (const float*)d_in[1];
    float* out      = (float*)d_out;
    float* dispatch = out;
    float* combine  = out + (size_t)Tm * Em;
    float* probs    = out + 2 * (size_t)Tm * Em;

    const size_t wtB = sizeof(float) * (size_t)Hm * Em;   // 512 KB
    const size_t teB = sizeof(float) * (size_t)Tm * Em;   // 8 MB
    char* ws = (char*)d_ws;

    float* Wt = (float*)ws;
    size_t off = wtB;

    // pick largest split-K that fits: partials (nkq*teB) + probsT (teB)
    int nkq = 1;
    if      (ws_size >= off + 8 * teB + teB) nkq = 8;
    else if (ws_size >= off + 4 * teB + teB) nkq = 4;
    else if (ws_size >= off + 2 * teB + teB) nkq = 2;

    float* pl = (float*)(ws + off);
    off += (size_t)nkq * teB;

    float* probsT = nullptr;
    if (ws_size >= off + teB) { probsT = (float*)(ws + off); off += teB; }
    float* dT = nullptr;
    if (ws_size >= off + teB) { dT = (float*)(ws + off); off += teB; }

    if (!dT)
        hipMemsetAsync(dispatch, 0, teB, stream);

    k_wt<<<Hm / 64, 256, 0, stream>>>(W, Wt);
    k_router_partial<<<256 * nkq, 128, 0, stream>>>(hid, Wt, pl, nkq);
    k_reduce<<<Tm / 256, 256, 0, stream>>>(pl, nkq, probs, probsT);
    k_select<<<Em, 1024, 0, stream>>>(probsT, probs, dispatch, dT);
    if (dT) k_finish<<<Tm / 64, 256, 0, stream>>>(dT, dispatch, combine);
    else    k_combine<<<Tm / 4, 256, 0, stream>>>(dispatch, combine);
}

// Round 6
// 176.513 us; speedup vs baseline: 3.8347x; 3.8347x over previous
//
#include <hip/hip_runtime.h>

#define Hm 2048
#define Em 64
#define Tm 32768
#define KSEL 640        // int(1.25 * 32768 / 64)
#define CHK 16          // k per staged chunk

typedef unsigned int u32;

__device__ __forceinline__ float4 ld4(const float* p) {
    return *reinterpret_cast<const float4*>(p);
}

// ---------------------------------------------------------------------------
// K0: W [64][2048] -> Wt [2048][64] (k-major, one-time)
// ---------------------------------------------------------------------------
__global__ __launch_bounds__(256) void k_wt(
    const float* __restrict__ W, float* __restrict__ Wt)
{
    __shared__ float T[64][65];
    const int tid = threadIdx.x;
    const int kb = blockIdx.x * 64;
    const int lc = tid & 63;
    const int lr = tid >> 6;
#pragma unroll
    for (int r = 0; r < 16; ++r) {
        const int e = r * 4 + lr;
        T[e][lc] = W[(size_t)e * Hm + kb + lc];
    }
    __syncthreads();
#pragma unroll
    for (int r = 0; r < 16; ++r) {
        const int kk = r * 4 + lr;
        Wt[(size_t)(kb + kk) * Em + lc] = T[lc][kk];
    }
}

// ---------------------------------------------------------------------------
// K1: split-K partial GEMM. grid = 256*nkq blocks x 128 threads (2 waves).
// Wave = 64 tok x 64 exp; thread tile = 8 tok x 8 exp (lane grid 8x8) ->
// every LDS fragment read is 8-way broadcast, 2-way bank alias (free).
// A staged k-major As[k][tok] via stride-1 scalar writes; B linear copy.
// Partials pl[kq][T][E] (fp32) reduced by k_reduce.
// NOTE: launch_bounds (128, 2): acc[8][8]=64 VGPR tile; the (128,4) cap in
// round 5 made the allocator spill acc to scratch (VGPR=64, 2.6 GB HBM of
// spill traffic, 650 us). 2 waves/EU -> 256 VGPR budget; occupancy comes
// from 8 co-resident blocks (LDS 12.8 KB each).
// ---------------------------------------------------------------------------
__global__ __launch_bounds__(128, 2) void k_router_partial(
    const float* __restrict__ hid, const float* __restrict__ Wt,
    float* __restrict__ pl, int nkq)
{
    __shared__ __align__(16) float As[CHK][132];   // 8.4 KB (k-major, pad 4)
    __shared__ __align__(16) float Bs[CHK][68];    // 4.3 KB

    const int t = threadIdx.x;
    const int tb = blockIdx.x & 255;
    const int kq = blockIdx.x >> 8;
    const int t0 = tb * 128;
    const int k0 = kq * (Hm / nkq);
    const int nchunks = (Hm / nkq) / CHK;

    const float* ap = hid + (size_t)(t0 + t) * Hm + k0;
    const float* bp = Wt + (size_t)k0 * Em + t * 8;

    float acc[8][8];
#pragma unroll
    for (int i = 0; i < 8; ++i)
#pragma unroll
        for (int j = 0; j < 8; ++j) acc[i][j] = 0.f;

    float ar[16];
    float4 br0, br1;

    auto loadA = [&](int c) {
#pragma unroll
        for (int u = 0; u < 4; ++u) {
            const float4 v = ld4(ap + c * CHK + 4 * u);
            ar[4 * u + 0] = v.x; ar[4 * u + 1] = v.y;
            ar[4 * u + 2] = v.z; ar[4 * u + 3] = v.w;
        }
    };
    auto loadB = [&](int c) {
        const float* b = bp + (size_t)c * (CHK * Em);
        br0 = ld4(b);
        br1 = ld4(b + 4);
    };
    auto writeAB = [&]() {
#pragma unroll
        for (int kk = 0; kk < CHK; ++kk) As[kk][t] = ar[kk];
        *reinterpret_cast<float4*>(&Bs[t >> 3][(t & 7) * 8])     = br0;
        *reinterpret_cast<float4*>(&Bs[t >> 3][(t & 7) * 8 + 4]) = br1;
    };

    const int l  = t & 63;
    const int w  = t >> 6;
    const int lr = l >> 3;
    const int lc = l & 7;
    const int ta = w * 64 + lr * 8;   // token base within block tile

    loadA(0); loadB(0);

    for (int c = 0; c < nchunks; ++c) {
        writeAB();
        __syncthreads();
        if (c + 1 < nchunks) { loadA(c + 1); loadB(c + 1); }

#pragma unroll
        for (int kk = 0; kk < CHK; ++kk) {
            const float4 a0 = ld4(&As[kk][ta]);
            const float4 a1 = ld4(&As[kk][ta + 4]);
            const float4 b0 = ld4(&Bs[kk][lc * 8]);
            const float4 b1 = ld4(&Bs[kk][lc * 8 + 4]);
            const float av[8] = { a0.x, a0.y, a0.z, a0.w,
                                  a1.x, a1.y, a1.z, a1.w };
            const float bv[8] = { b0.x, b0.y, b0.z, b0.w,
                                  b1.x, b1.y, b1.z, b1.w };
#pragma unroll
            for (int i = 0; i < 8; ++i)
#pragma unroll
                for (int j = 0; j < 8; ++j)
                    acc[i][j] = fmaf(av[i], bv[j], acc[i][j]);
        }
        __syncthreads();
    }

    // epilogue: write partials
#pragma unroll
    for (int i = 0; i < 8; ++i) {
        float* dst = pl + ((size_t)kq * Tm + t0 + ta + i) * Em + lc * 8;
        *reinterpret_cast<float4*>(dst) =
            make_float4(acc[i][0], acc[i][1], acc[i][2], acc[i][3]);
        *reinterpret_cast<float4*>(dst + 4) =
            make_float4(acc[i][4], acc[i][5], acc[i][6], acc[i][7]);
    }
}

// ---------------------------------------------------------------------------
// K1b: reduce split-K partials + softmax. One thread per token.
// grid = 128 x 256. Writes probs [T][E] and probsT [E][T] (coalesced).
// ---------------------------------------------------------------------------
__global__ __launch_bounds__(256) void k_reduce(
    const float* __restrict__ pl, int nkq,
    float* __restrict__ probs, float* __restrict__ probsT)
{
    const int t = blockIdx.x * 256 + threadIdx.x;
    float lg[64];
    {
        const float* src = pl + (size_t)t * Em;
#pragma unroll
        for (int j = 0; j < 16; ++j) {
            const float4 x = ld4(src + 4 * j);
            lg[4 * j + 0] = x.x; lg[4 * j + 1] = x.y;
            lg[4 * j + 2] = x.z; lg[4 * j + 3] = x.w;
        }
    }
    for (int q = 1; q < nkq; ++q) {
        const float* src = pl + ((size_t)q * Tm + t) * Em;
#pragma unroll
        for (int j = 0; j < 16; ++j) {
            const float4 x = ld4(src + 4 * j);
            lg[4 * j + 0] += x.x; lg[4 * j + 1] += x.y;
            lg[4 * j + 2] += x.z; lg[4 * j + 3] += x.w;
        }
    }
    float mx = lg[0];
#pragma unroll
    for (int e = 1; e < 64; ++e) mx = fmaxf(mx, lg[e]);
    float s = 0.f;
#pragma unroll
    for (int e = 0; e < 64; ++e) { lg[e] = __expf(lg[e] - mx); s += lg[e]; }
    const float inv = 1.0f / s;
#pragma unroll
    for (int e = 0; e < 64; ++e) lg[e] *= inv;

    float* po = probs + (size_t)t * Em;
#pragma unroll
    for (int j = 0; j < 16; ++j)
        *reinterpret_cast<float4*>(po + 4 * j) =
            make_float4(lg[4 * j], lg[4 * j + 1], lg[4 * j + 2], lg[4 * j + 3]);
    if (probsT) {
#pragma unroll
        for (int e = 0; e < 64; ++e)
            probsT[(size_t)e * Tm + t] = lg[e];
    }
}

// ---------------------------------------------------------------------------
// K2: per-expert top-640 radix select (10/11/11 bits).
// dT path: write full coalesced rows dT[e][t] (no pre-zero needed).
// ---------------------------------------------------------------------------
__device__ __forceinline__ void suffix_scan(u32* h, int nbins) {
    const int tid = threadIdx.x;
    for (int off = 1; off < nbins; off <<= 1) {
        u32 v0 = 0, v1 = 0;
        const int b0 = tid, b1 = tid + 1024;
        if (b0 < nbins) v0 = h[b0] + ((b0 + off) < nbins ? h[b0 + off] : 0u);
        if (b1 < nbins) v1 = h[b1] + ((b1 + off) < nbins ? h[b1 + off] : 0u);
        __syncthreads();
        if (b0 < nbins) h[b0] = v0;
        if (b1 < nbins) h[b1] = v1;
        __syncthreads();
    }
}

__global__ __launch_bounds__(1024) void k_select(
    const float* __restrict__ probsT, const float* __restrict__ probsRM,
    float* __restrict__ dispatch, float* __restrict__ dT)
{
    __shared__ u32 keys[Tm];        // 128 KB
    __shared__ u32 hist[2048];      // 8 KB (reused as tie list)
    __shared__ u32 sh_need[4];
    __shared__ u32 sh_bins[3];
    __shared__ u32 sh_ntie, sh_take, sh_nlist;

    const int tid = threadIdx.x;
    const int e = blockIdx.x;

    if (probsT) {
        const float4* src = reinterpret_cast<const float4*>(probsT + (size_t)e * Tm);
        for (int i = tid; i < Tm / 4; i += 1024) {
            float4 x = src[i];
            uint4 kk = make_uint4(__float_as_uint(x.x), __float_as_uint(x.y),
                                  __float_as_uint(x.z), __float_as_uint(x.w));
            *reinterpret_cast<uint4*>(&keys[4 * i]) = kk;
        }
    } else {
        for (int t = tid; t < Tm; t += 1024)
            keys[t] = __float_as_uint(probsRM[(size_t)t * Em + e]);
    }

    // pass 1: bits [31:22]
    hist[tid] = 0;
    if (tid == 0) sh_need[0] = KSEL;
    __syncthreads();
    for (int t = tid; t < Tm; t += 1024)
        atomicAdd(&hist[keys[t] >> 22], 1u);
    __syncthreads();
    suffix_scan(hist, 1024);
    {
        const u32 need = sh_need[0];
        if (tid < 1024) {
            const u32 sb = hist[tid];
            const u32 sa = (tid + 1 < 1024) ? hist[tid + 1] : 0u;
            if (sb >= need && sa < need) { sh_bins[0] = (u32)tid; sh_need[1] = need - sa; }
        }
    }
    __syncthreads();
    const u32 b1 = sh_bins[0];

    // pass 2: bits [21:11]
    hist[tid] = 0; hist[tid + 1024] = 0;
    __syncthreads();
    for (int t = tid; t < Tm; t += 1024) {
        const u32 k = keys[t];
        if ((k >> 22) == b1) atomicAdd(&hist[(k >> 11) & 0x7FFu], 1u);
    }
    __syncthreads();
    suffix_scan(hist, 2048);
    {
        const u32 need = sh_need[1];
#pragma unroll
        for (int r = 0; r < 2; ++r) {
            const int b = tid + r * 1024;
            const u32 sb = hist[b];
            const u32 sa = (b + 1 < 2048) ? hist[b + 1] : 0u;
            if (sb >= need && sa < need) { sh_bins[1] = (u32)b; sh_need[2] = need - sa; }
        }
    }
    __syncthreads();
    const u32 p2 = (b1 << 11) | sh_bins[1];

    // pass 3: bits [10:0]
    hist[tid] = 0; hist[tid + 1024] = 0;
    __syncthreads();
    for (int t = tid; t < Tm; t += 1024) {
        const u32 k = keys[t];
        if ((k >> 11) == p2) atomicAdd(&hist[k & 0x7FFu], 1u);
    }
    __syncthreads();
    suffix_scan(hist, 2048);
    {
        const u32 need = sh_need[2];
#pragma unroll
        for (int r = 0; r < 2; ++r) {
            const int b = tid + r * 1024;
            const u32 sb = hist[b];
            const u32 sa = (b + 1 < 2048) ? hist[b + 1] : 0u;
            if (sb >= need && sa < need) {
                sh_bins[2] = (u32)b;
                sh_take = need - sa;
                sh_ntie = sb - sa;
            }
        }
    }
    __syncthreads();
    const u32 Kstar = (p2 << 11) | sh_bins[2];
    const u32 take = sh_take, ntie = sh_ntie;

    if (dT) {
        float* drow = dT + (size_t)e * Tm;
        if (ntie == take) {
            for (int t = tid; t < Tm; t += 1024) {
                const u32 k = keys[t];
                drow[t] = (k >= Kstar) ? __uint_as_float(k) : 0.f;
            }
        } else {
            if (tid == 0) sh_nlist = 0;
            __syncthreads();
            for (int t = tid; t < Tm; t += 1024) {
                const u32 k = keys[t];
                drow[t] = (k > Kstar) ? __uint_as_float(k) : 0.f;
                if (k == Kstar) {
                    const u32 idx = atomicAdd(&sh_nlist, 1u);
                    if (idx < 2048u) hist[idx] = (u32)t;
                }
            }
            __syncthreads();
            const int n = (int)(sh_nlist < 2048u ? sh_nlist : 2048u);
            for (int i = tid; i < n; i += 1024) {
                const u32 t = hist[i];
                int r = 0;
                for (int j = 0; j < n; ++j) r += (hist[j] < t);
                if (r < (int)take) drow[t] = __uint_as_float(Kstar);
            }
        }
    } else {
        if (ntie == take) {
            for (int t = tid; t < Tm; t += 1024) {
                const u32 k = keys[t];
                if (k >= Kstar) dispatch[(size_t)t * Em + e] = __uint_as_float(k);
            }
        } else {
            if (tid == 0) sh_nlist = 0;
            __syncthreads();
            for (int t = tid; t < Tm; t += 1024) {
                const u32 k = keys[t];
                if (k > Kstar) {
                    dispatch[(size_t)t * Em + e] = __uint_as_float(k);
                } else if (k == Kstar) {
                    const u32 idx = atomicAdd(&sh_nlist, 1u);
                    if (idx < 2048u) hist[idx] = (u32)t;
                }
            }
            __syncthreads();
            const int n = (int)(sh_nlist < 2048u ? sh_nlist : 2048u);
            for (int i = tid; i < n; i += 1024) {
                const u32 t = hist[i];
                int r = 0;
                for (int j = 0; j < n; ++j) r += (hist[j] < t);
                if (r < (int)take)
                    dispatch[(size_t)t * Em + e] = __uint_as_float(Kstar);
            }
        }
    }
}

// ---------------------------------------------------------------------------
// K3a (dT path): transpose dT [E][T] -> dispatch [T][E] + combine, fused.
// ---------------------------------------------------------------------------
__global__ __launch_bounds__(256) void k_finish(
    const float* __restrict__ dT, float* __restrict__ dispatch,
    float* __restrict__ combine)
{
    __shared__ float Ls[64][65];
    const int tid = threadIdx.x;
    const int t0 = blockIdx.x * 64;
    {
        const int e = tid >> 2, tq = tid & 3;
        const float* src = dT + (size_t)e * Tm + t0 + tq * 16;
#pragma unroll
        for (int u = 0; u < 4; ++u) {
            const float4 x = ld4(src + 4 * u);
            Ls[tq * 16 + 4 * u + 0][e] = x.x;
            Ls[tq * 16 + 4 * u + 1][e] = x.y;
            Ls[tq * 16 + 4 * u + 2][e] = x.z;
            Ls[tq * 16 + 4 * u + 3][e] = x.w;
        }
    }
    __syncthreads();
    const int t = tid >> 2, q = tid & 3;
    float v[16];
    float s = 0.f;
#pragma unroll
    for (int u = 0; u < 16; ++u) { v[u] = Ls[t][q * 16 + u]; s += v[u]; }
    s += __shfl_xor(s, 1, 4);
    s += __shfl_xor(s, 2, 4);
    const float inv = (s > 0.f) ? 1.0f / s : 0.f;
    float* dp = dispatch + (size_t)(t0 + t) * Em + q * 16;
    float* cb = combine  + (size_t)(t0 + t) * Em + q * 16;
#pragma unroll
    for (int u = 0; u < 4; ++u) {
        *reinterpret_cast<float4*>(dp + 4 * u) =
            make_float4(v[4 * u], v[4 * u + 1], v[4 * u + 2], v[4 * u + 3]);
        *reinterpret_cast<float4*>(cb + 4 * u) =
            make_float4(v[4 * u] * inv, v[4 * u + 1] * inv,
                        v[4 * u + 2] * inv, v[4 * u + 3] * inv);
    }
}

// ---------------------------------------------------------------------------
// K3b (fallback): combine from dispatch rows.
// ---------------------------------------------------------------------------
__global__ __launch_bounds__(256) void k_combine(
    const float* __restrict__ dispatch, float* __restrict__ combine)
{
    const int wid = threadIdx.x >> 6;
    const int lane = threadIdx.x & 63;
    const int t = blockIdx.x * 4 + wid;
    const float d = dispatch[(size_t)t * Em + lane];
    float s = d;
#pragma unroll
    for (int off = 32; off > 0; off >>= 1) s += __shfl_xor(s, off, 64);
    combine[(size_t)t * Em + lane] = (s > 0.f) ? d / s : 0.f;
}

// ---------------------------------------------------------------------------
extern "C" void kernel_launch(void* const* d_in, const int* in_sizes, int n_in,
                              void* d_out, int out_size, void* d_ws, size_t ws_size,
                              hipStream_t stream) {
    const float* hid = (const float*)d_in[0];
    const float* W   = (const float*)d_in[1];
    float* out      = (float*)d_out;
    float* dispatch = out;
    float* combine  = out + (size_t)Tm * Em;
    float* probs    = out + 2 * (size_t)Tm * Em;

    const size_t wtB = sizeof(float) * (size_t)Hm * Em;   // 512 KB
    const size_t teB = sizeof(float) * (size_t)Tm * Em;   // 8 MB
    char* ws = (char*)d_ws;

    float* Wt = (float*)ws;
    size_t off = wtB;

    // pick largest split-K that fits: partials (nkq*teB) + probsT (teB)
    int nkq = 1;
    if      (ws_size >= off + 8 * teB + teB) nkq = 8;
    else if (ws_size >= off + 4 * teB + teB) nkq = 4;
    else if (ws_size >= off + 2 * teB + teB) nkq = 2;

    float* pl = (float*)(ws + off);
    off += (size_t)nkq * teB;

    float* probsT = nullptr;
    if (ws_size >= off + teB) { probsT = (float*)(ws + off); off += teB; }
    float* dT = nullptr;
    if (ws_size >= off + teB) { dT = (float*)(ws + off); off += teB; }

    if (!dT)
        hipMemsetAsync(dispatch, 0, teB, stream);

    k_wt<<<Hm / 64, 256, 0, stream>>>(W, Wt);
    k_router_partial<<<256 * nkq, 128, 0, stream>>>(hid, Wt, pl, nkq);
    k_reduce<<<Tm / 256, 256, 0, stream>>>(pl, nkq, probs, probsT);
    k_select<<<Em, 1024, 0, stream>>>(probsT, probs, dispatch, dT);
    if (dT) k_finish<<<Tm / 64, 256, 0, stream>>>(dT, dispatch, combine);
    else    k_combine<<<Tm / 4, 256, 0, stream>>>(dispatch, combine);
}

// Round 7
// 166.935 us; speedup vs baseline: 4.0547x; 1.0574x over previous
//
#include <hip/hip_runtime.h>

#define Hm 2048
#define Em 64
#define Tm 32768
#define KSEL 640        // int(1.25 * 32768 / 64)
#define CHK 16          // k per staged chunk

typedef unsigned int u32;

__device__ __forceinline__ float4 ld4(const float* p) {
    return *reinterpret_cast<const float4*>(p);
}

// ---------------------------------------------------------------------------
// K0: W [64][2048] -> Wt [2048][64] (k-major, one-time)
// ---------------------------------------------------------------------------
__global__ __launch_bounds__(256) void k_wt(
    const float* __restrict__ W, float* __restrict__ Wt)
{
    __shared__ float T[64][65];
    const int tid = threadIdx.x;
    const int kb = blockIdx.x * 64;
    const int lc = tid & 63;
    const int lr = tid >> 6;
#pragma unroll
    for (int r = 0; r < 16; ++r) {
        const int e = r * 4 + lr;
        T[e][lc] = W[(size_t)e * Hm + kb + lc];
    }
    __syncthreads();
#pragma unroll
    for (int r = 0; r < 16; ++r) {
        const int kk = r * 4 + lr;
        Wt[(size_t)(kb + kk) * Em + lc] = T[lc][kk];
    }
}

// ---------------------------------------------------------------------------
// K1: split-K partial GEMM (UNCHANGED from round 6 — A/B control).
// ---------------------------------------------------------------------------
__global__ __launch_bounds__(128, 2) void k_router_partial(
    const float* __restrict__ hid, const float* __restrict__ Wt,
    float* __restrict__ pl, int nkq)
{
    __shared__ __align__(16) float As[CHK][132];   // 8.4 KB (k-major, pad 4)
    __shared__ __align__(16) float Bs[CHK][68];    // 4.3 KB

    const int t = threadIdx.x;
    const int tb = blockIdx.x & 255;
    const int kq = blockIdx.x >> 8;
    const int t0 = tb * 128;
    const int k0 = kq * (Hm / nkq);
    const int nchunks = (Hm / nkq) / CHK;

    const float* ap = hid + (size_t)(t0 + t) * Hm + k0;
    const float* bp = Wt + (size_t)k0 * Em + t * 8;

    float acc[8][8];
#pragma unroll
    for (int i = 0; i < 8; ++i)
#pragma unroll
        for (int j = 0; j < 8; ++j) acc[i][j] = 0.f;

    float ar[16];
    float4 br0, br1;

    auto loadA = [&](int c) {
#pragma unroll
        for (int u = 0; u < 4; ++u) {
            const float4 v = ld4(ap + c * CHK + 4 * u);
            ar[4 * u + 0] = v.x; ar[4 * u + 1] = v.y;
            ar[4 * u + 2] = v.z; ar[4 * u + 3] = v.w;
        }
    };
    auto loadB = [&](int c) {
        const float* b = bp + (size_t)c * (CHK * Em);
        br0 = ld4(b);
        br1 = ld4(b + 4);
    };
    auto writeAB = [&]() {
#pragma unroll
        for (int kk = 0; kk < CHK; ++kk) As[kk][t] = ar[kk];
        *reinterpret_cast<float4*>(&Bs[t >> 3][(t & 7) * 8])     = br0;
        *reinterpret_cast<float4*>(&Bs[t >> 3][(t & 7) * 8 + 4]) = br1;
    };

    const int l  = t & 63;
    const int w  = t >> 6;
    const int lr = l >> 3;
    const int lc = l & 7;
    const int ta = w * 64 + lr * 8;   // token base within block tile

    loadA(0); loadB(0);

    for (int c = 0; c < nchunks; ++c) {
        writeAB();
        __syncthreads();
        if (c + 1 < nchunks) { loadA(c + 1); loadB(c + 1); }

#pragma unroll
        for (int kk = 0; kk < CHK; ++kk) {
            const float4 a0 = ld4(&As[kk][ta]);
            const float4 a1 = ld4(&As[kk][ta + 4]);
            const float4 b0 = ld4(&Bs[kk][lc * 8]);
            const float4 b1 = ld4(&Bs[kk][lc * 8 + 4]);
            const float av[8] = { a0.x, a0.y, a0.z, a0.w,
                                  a1.x, a1.y, a1.z, a1.w };
            const float bv[8] = { b0.x, b0.y, b0.z, b0.w,
                                  b1.x, b1.y, b1.z, b1.w };
#pragma unroll
            for (int i = 0; i < 8; ++i)
#pragma unroll
                for (int j = 0; j < 8; ++j)
                    acc[i][j] = fmaf(av[i], bv[j], acc[i][j]);
        }
        __syncthreads();
    }

    // epilogue: write partials
#pragma unroll
    for (int i = 0; i < 8; ++i) {
        float* dst = pl + ((size_t)kq * Tm + t0 + ta + i) * Em + lc * 8;
        *reinterpret_cast<float4*>(dst) =
            make_float4(acc[i][0], acc[i][1], acc[i][2], acc[i][3]);
        *reinterpret_cast<float4*>(dst + 4) =
            make_float4(acc[i][4], acc[i][5], acc[i][6], acc[i][7]);
    }
}

// ---------------------------------------------------------------------------
// K1b: reduce split-K partials + softmax. One thread per token.
// grid = 256 x 128 (all CUs; was 128 x 256 using only half).
// ---------------------------------------------------------------------------
__global__ __launch_bounds__(128) void k_reduce(
    const float* __restrict__ pl, int nkq,
    float* __restrict__ probs, float* __restrict__ probsT)
{
    const int t = blockIdx.x * 128 + threadIdx.x;
    float lg[64];
    {
        const float* src = pl + (size_t)t * Em;
#pragma unroll
        for (int j = 0; j < 16; ++j) {
            const float4 x = ld4(src + 4 * j);
            lg[4 * j + 0] = x.x; lg[4 * j + 1] = x.y;
            lg[4 * j + 2] = x.z; lg[4 * j + 3] = x.w;
        }
    }
    for (int q = 1; q < nkq; ++q) {
        const float* src = pl + ((size_t)q * Tm + t) * Em;
#pragma unroll
        for (int j = 0; j < 16; ++j) {
            const float4 x = ld4(src + 4 * j);
            lg[4 * j + 0] += x.x; lg[4 * j + 1] += x.y;
            lg[4 * j + 2] += x.z; lg[4 * j + 3] += x.w;
        }
    }
    float mx = lg[0];
#pragma unroll
    for (int e = 1; e < 64; ++e) mx = fmaxf(mx, lg[e]);
    float s = 0.f;
#pragma unroll
    for (int e = 0; e < 64; ++e) { lg[e] = __expf(lg[e] - mx); s += lg[e]; }
    const float inv = 1.0f / s;
#pragma unroll
    for (int e = 0; e < 64; ++e) lg[e] *= inv;

    float* po = probs + (size_t)t * Em;
#pragma unroll
    for (int j = 0; j < 16; ++j)
        *reinterpret_cast<float4*>(po + 4 * j) =
            make_float4(lg[4 * j], lg[4 * j + 1], lg[4 * j + 2], lg[4 * j + 3]);
    if (probsT) {
#pragma unroll
        for (int e = 0; e < 64; ++e)
            probsT[(size_t)e * Tm + t] = lg[e];
    }
}

// ---------------------------------------------------------------------------
// K2: per-expert top-640 radix select, passes 11/11/10 bits.
// Hierarchical suffix scan: 2 barriers/pass (was 22).
// ---------------------------------------------------------------------------
__device__ __forceinline__ void suffix_scan_fast(u32* h, u32* wsum, int nbins) {
    // 1024 threads. Each thread owns R = nbins/1024 consecutive bins.
    const int tid  = threadIdx.x;
    const int lane = tid & 63;
    const int w    = tid >> 6;
    u32 a0, a1, s;
    if (nbins == 2048) {
        a0 = h[2 * tid]; a1 = h[2 * tid + 1]; s = a0 + a1;
    } else {
        a0 = h[tid]; a1 = 0; s = a0;
    }
    // wave-level inclusive suffix scan of s
    u32 v = s;
#pragma unroll
    for (int off = 1; off < 64; off <<= 1) {
        const u32 tv = __shfl_down(v, off, 64);
        if (lane + off < 64) v += tv;
    }
    if (lane == 0) wsum[w] = v;      // wave total
    __syncthreads();
    u32 woff = 0;                    // sum of totals of later waves
#pragma unroll
    for (int j = 0; j < 16; ++j) woff += (j > w) ? wsum[j] : 0u;
    const u32 after = v - s + woff;  // sum over threads strictly after tid
    if (nbins == 2048) {
        h[2 * tid]     = after + s;      // suffix incl. bin 2*tid
        h[2 * tid + 1] = after + a1;     // suffix incl. bin 2*tid+1
    } else {
        h[tid] = after + s;
    }
    __syncthreads();
}

__global__ __launch_bounds__(1024) void k_select(
    const float* __restrict__ probsT, const float* __restrict__ probsRM,
    float* __restrict__ dispatch, float* __restrict__ dT)
{
    __shared__ u32 keys[Tm];        // 128 KB
    __shared__ u32 hist[2048];      // 8 KB (reused as tie list)
    __shared__ u32 wsum[16];
    __shared__ u32 sh_need[4];
    __shared__ u32 sh_bins[3];
    __shared__ u32 sh_ntie, sh_take, sh_nlist;

    const int tid = threadIdx.x;
    const int e = blockIdx.x;

    if (probsT) {
        const float4* src = reinterpret_cast<const float4*>(probsT + (size_t)e * Tm);
        for (int i = tid; i < Tm / 4; i += 1024) {
            float4 x = src[i];
            uint4 kk = make_uint4(__float_as_uint(x.x), __float_as_uint(x.y),
                                  __float_as_uint(x.z), __float_as_uint(x.w));
            *reinterpret_cast<uint4*>(&keys[4 * i]) = kk;
        }
    } else {
        for (int t = tid; t < Tm; t += 1024)
            keys[t] = __float_as_uint(probsRM[(size_t)t * Em + e]);
    }

    // ---- pass 1: bits [31:21], 2048 bins ----
    hist[tid] = 0; hist[tid + 1024] = 0;
    if (tid == 0) sh_need[0] = KSEL;
    __syncthreads();
    for (int t = tid; t < Tm; t += 1024)
        atomicAdd(&hist[keys[t] >> 21], 1u);
    __syncthreads();
    suffix_scan_fast(hist, wsum, 2048);
    {
        const u32 need = sh_need[0];
#pragma unroll
        for (int r = 0; r < 2; ++r) {
            const int b = tid + r * 1024;
            const u32 sb = hist[b];
            const u32 sa = (b + 1 < 2048) ? hist[b + 1] : 0u;
            if (sb >= need && sa < need) { sh_bins[0] = (u32)b; sh_need[1] = need - sa; }
        }
    }
    __syncthreads();
    const u32 b1 = sh_bins[0];

    // ---- pass 2: bits [20:10], 2048 bins ----
    hist[tid] = 0; hist[tid + 1024] = 0;
    __syncthreads();
    for (int t = tid; t < Tm; t += 1024) {
        const u32 k = keys[t];
        if ((k >> 21) == b1) atomicAdd(&hist[(k >> 10) & 0x7FFu], 1u);
    }
    __syncthreads();
    suffix_scan_fast(hist, wsum, 2048);
    {
        const u32 need = sh_need[1];
#pragma unroll
        for (int r = 0; r < 2; ++r) {
            const int b = tid + r * 1024;
            const u32 sb = hist[b];
            const u32 sa = (b + 1 < 2048) ? hist[b + 1] : 0u;
            if (sb >= need && sa < need) { sh_bins[1] = (u32)b; sh_need[2] = need - sa; }
        }
    }
    __syncthreads();
    const u32 p2 = (b1 << 11) | sh_bins[1];

    // ---- pass 3: bits [9:0], 1024 bins ----
    hist[tid] = 0;
    __syncthreads();
    for (int t = tid; t < Tm; t += 1024) {
        const u32 k = keys[t];
        if ((k >> 10) == p2) atomicAdd(&hist[k & 0x3FFu], 1u);
    }
    __syncthreads();
    suffix_scan_fast(hist, wsum, 1024);
    {
        const u32 need = sh_need[2];
        const u32 sb = hist[tid];
        const u32 sa = (tid + 1 < 1024) ? hist[tid + 1] : 0u;
        if (sb >= need && sa < need) {
            sh_bins[2] = (u32)tid;
            sh_take = need - sa;      // ties (== Kstar) to include
            sh_ntie = sb - sa;        // total ties
        }
    }
    __syncthreads();
    const u32 Kstar = (p2 << 10) | sh_bins[2];
    const u32 take = sh_take, ntie = sh_ntie;

    if (dT) {
        float* drow = dT + (size_t)e * Tm;
        if (ntie == take) {
            for (int t = tid; t < Tm; t += 1024) {
                const u32 k = keys[t];
                drow[t] = (k >= Kstar) ? __uint_as_float(k) : 0.f;
            }
        } else {
            if (tid == 0) sh_nlist = 0;
            __syncthreads();
            for (int t = tid; t < Tm; t += 1024) {
                const u32 k = keys[t];
                drow[t] = (k > Kstar) ? __uint_as_float(k) : 0.f;
                if (k == Kstar) {
                    const u32 idx = atomicAdd(&sh_nlist, 1u);
                    if (idx < 2048u) hist[idx] = (u32)t;
                }
            }
            __syncthreads();
            const int n = (int)(sh_nlist < 2048u ? sh_nlist : 2048u);
            for (int i = tid; i < n; i += 1024) {
                const u32 t = hist[i];
                int r = 0;
                for (int j = 0; j < n; ++j) r += (hist[j] < t);
                if (r < (int)take) drow[t] = __uint_as_float(Kstar);
            }
        }
    } else {
        if (ntie == take) {
            for (int t = tid; t < Tm; t += 1024) {
                const u32 k = keys[t];
                if (k >= Kstar) dispatch[(size_t)t * Em + e] = __uint_as_float(k);
            }
        } else {
            if (tid == 0) sh_nlist = 0;
            __syncthreads();
            for (int t = tid; t < Tm; t += 1024) {
                const u32 k = keys[t];
                if (k > Kstar) {
                    dispatch[(size_t)t * Em + e] = __uint_as_float(k);
                } else if (k == Kstar) {
                    const u32 idx = atomicAdd(&sh_nlist, 1u);
                    if (idx < 2048u) hist[idx] = (u32)t;
                }
            }
            __syncthreads();
            const int n = (int)(sh_nlist < 2048u ? sh_nlist : 2048u);
            for (int i = tid; i < n; i += 1024) {
                const u32 t = hist[i];
                int r = 0;
                for (int j = 0; j < n; ++j) r += (hist[j] < t);
                if (r < (int)take)
                    dispatch[(size_t)t * Em + e] = __uint_as_float(Kstar);
            }
        }
    }
}

// ---------------------------------------------------------------------------
// K3a (dT path): transpose dT [E][T] -> dispatch [T][E] + combine, fused.
// ---------------------------------------------------------------------------
__global__ __launch_bounds__(256) void k_finish(
    const float* __restrict__ dT, float* __restrict__ dispatch,
    float* __restrict__ combine)
{
    __shared__ float Ls[64][65];
    const int tid = threadIdx.x;
    const int t0 = blockIdx.x * 64;
    {
        const int e = tid >> 2, tq = tid & 3;
        const float* src = dT + (size_t)e * Tm + t0 + tq * 16;
#pragma unroll
        for (int u = 0; u < 4; ++u) {
            const float4 x = ld4(src + 4 * u);
            Ls[tq * 16 + 4 * u + 0][e] = x.x;
            Ls[tq * 16 + 4 * u + 1][e] = x.y;
            Ls[tq * 16 + 4 * u + 2][e] = x.z;
            Ls[tq * 16 + 4 * u + 3][e] = x.w;
        }
    }
    __syncthreads();
    const int t = tid >> 2, q = tid & 3;
    float v[16];
    float s = 0.f;
#pragma unroll
    for (int u = 0; u < 16; ++u) { v[u] = Ls[t][q * 16 + u]; s += v[u]; }
    s += __shfl_xor(s, 1, 4);
    s += __shfl_xor(s, 2, 4);
    const float inv = (s > 0.f) ? 1.0f / s : 0.f;
    float* dp = dispatch + (size_t)(t0 + t) * Em + q * 16;
    float* cb = combine  + (size_t)(t0 + t) * Em + q * 16;
#pragma unroll
    for (int u = 0; u < 4; ++u) {
        *reinterpret_cast<float4*>(dp + 4 * u) =
            make_float4(v[4 * u], v[4 * u + 1], v[4 * u + 2], v[4 * u + 3]);
        *reinterpret_cast<float4*>(cb + 4 * u) =
            make_float4(v[4 * u] * inv, v[4 * u + 1] * inv,
                        v[4 * u + 2] * inv, v[4 * u + 3] * inv);
    }
}

// ---------------------------------------------------------------------------
// K3b (fallback): combine from dispatch rows.
// ---------------------------------------------------------------------------
__global__ __launch_bounds__(256) void k_combine(
    const float* __restrict__ dispatch, float* __restrict__ combine)
{
    const int wid = threadIdx.x >> 6;
    const int lane = threadIdx.x & 63;
    const int t = blockIdx.x * 4 + wid;
    const float d = dispatch[(size_t)t * Em + lane];
    float s = d;
#pragma unroll
    for (int off = 32; off > 0; off >>= 1) s += __shfl_xor(s, off, 64);
    combine[(size_t)t * Em + lane] = (s > 0.f) ? d / s : 0.f;
}

// ---------------------------------------------------------------------------
extern "C" void kernel_launch(void* const* d_in, const int* in_sizes, int n_in,
                              void* d_out, int out_size, void* d_ws, size_t ws_size,
                              hipStream_t stream) {
    const float* hid = (const float*)d_in[0];
    const float* W   = (const float*)d_in[1];
    float* out      = (float*)d_out;
    float* dispatch = out;
    float* combine  = out + (size_t)Tm * Em;
    float* probs    = out + 2 * (size_t)Tm * Em;

    const size_t wtB = sizeof(float) * (size_t)Hm * Em;   // 512 KB
    const size_t teB = sizeof(float) * (size_t)Tm * Em;   // 8 MB
    char* ws = (char*)d_ws;

    float* Wt = (float*)ws;
    size_t off = wtB;

    // pick largest split-K that fits: partials (nkq*teB) + probsT (teB)
    int nkq = 1;
    if      (ws_size >= off + 8 * teB + teB) nkq = 8;
    else if (ws_size >= off + 4 * teB + teB) nkq = 4;
    else if (ws_size >= off + 2 * teB + teB) nkq = 2;

    float* pl = (float*)(ws + off);
    off += (size_t)nkq * teB;

    float* probsT = nullptr;
    if (ws_size >= off + teB) { probsT = (float*)(ws + off); off += teB; }
    float* dT = nullptr;
    if (ws_size >= off + teB) { dT = (float*)(ws + off); off += teB; }

    if (!dT)
        hipMemsetAsync(dispatch, 0, teB, stream);

    k_wt<<<Hm / 64, 256, 0, stream>>>(W, Wt);
    k_router_partial<<<256 * nkq, 128, 0, stream>>>(hid, Wt, pl, nkq);
    k_reduce<<<Tm / 128, 128, 0, stream>>>(pl, nkq, probs, probsT);
    k_select<<<Em, 1024, 0, stream>>>(probsT, probs, dispatch, dT);
    if (dT) k_finish<<<Tm / 64, 256, 0, stream>>>(dT, dispatch, combine);
    else    k_combine<<<Tm / 4, 256, 0, stream>>>(dispatch, combine);
}